// Round 6
// baseline (242.635 us; speedup 1.0000x reference)
//
#include <hip/hip_runtime.h>
#include <hip/hip_bf16.h>
#include <stdint.h>

#define BATCH 8192
#define DIM   512
#define TILE  128
#define NT    (BATCH / TILE)          // 64 tiles per dim
#define NPAIR (NT * (NT + 1) / 2)     // 2080 upper-triangle tile pairs

// Fb = F_norm * sqrt(log2(e)/T) so acc = Fb·Fbᵀ is already log2-domain logits.
#define FEAT_SCALE 4.5398164f         // sqrt(1.4426950409/0.07)
#define LN2        0.69314718055994531f

typedef __attribute__((ext_vector_type(8))) short short8;
typedef __attribute__((ext_vector_type(4))) float f32x4;

// ---------------------------------------------------------------------------
// Kernel 1: row-normalize fp32 -> bf16 * FEAT_SCALE. One wave per row.
// Also zeroes rowsum and the done-counter used by the fused finalize.
// ---------------------------------------------------------------------------
__global__ __launch_bounds__(256) void normalize_bf16(
    const float* __restrict__ x, __hip_bfloat16* __restrict__ o,
    float* __restrict__ rowsum, int* __restrict__ doneCount) {
  const int wv = threadIdx.x >> 6, lane = threadIdx.x & 63;
  const int row = blockIdx.x * 4 + wv;
  if (lane == 0) rowsum[row] = 0.0f;
  if (blockIdx.x == 0 && threadIdx.x == 0) *doneCount = 0;
  const float4* xr = (const float4*)(x + (size_t)row * DIM);
  const float4 v0 = xr[lane];
  const float4 v1 = xr[lane + 64];
  float ss = v0.x * v0.x + v0.y * v0.y + v0.z * v0.z + v0.w * v0.w +
             v1.x * v1.x + v1.y * v1.y + v1.z * v1.z + v1.w * v1.w;
#pragma unroll
  for (int m = 32; m > 0; m >>= 1) ss += __shfl_xor(ss, m, 64);
  const float inv = FEAT_SCALE / fmaxf(sqrtf(ss), 1e-12f);
  ushort4 p0, p1;
  p0.x = __bfloat16_as_ushort(__float2bfloat16(v0.x * inv));
  p0.y = __bfloat16_as_ushort(__float2bfloat16(v0.y * inv));
  p0.z = __bfloat16_as_ushort(__float2bfloat16(v0.z * inv));
  p0.w = __bfloat16_as_ushort(__float2bfloat16(v0.w * inv));
  p1.x = __bfloat16_as_ushort(__float2bfloat16(v1.x * inv));
  p1.y = __bfloat16_as_ushort(__float2bfloat16(v1.y * inv));
  p1.z = __bfloat16_as_ushort(__float2bfloat16(v1.z * inv));
  p1.w = __bfloat16_as_ushort(__float2bfloat16(v1.w * inv));
  ushort4* orow = (ushort4*)(o + (size_t)row * DIM);
  orow[lane]      = p0;
  orow[lane + 64] = p1;
}

// ---------------------------------------------------------------------------
// Kernel 2: BARRIER-FREE K-loop. MFMA fragments loaded straight from global
// (L2/L3-resident F): per lane, fragment = 16B at F + row*1024 + quad*16,
// k-chunk via immediate offset kc*64. No LDS, no __syncthreads until the
// epilogue -> the compiler pipelines loads across the whole K-loop with
// fine-grained vmcnt (the AITER pattern the barrier structure forbids).
// 2x read redundancy vs LDS staging, but all L2/L3 traffic.
// Epilogue: exp2 (log2-domain acc) -> LDS transpose reduce -> one global
// atomic per row-half; col sums (symmetry credit) via butterfly.
// Finalize fused: last block (device-scope done counter) computes the loss.
// ---------------------------------------------------------------------------
__global__ __launch_bounds__(256, 2) void sim_lse_kernel(
    const __hip_bfloat16* __restrict__ F, float* __restrict__ rowsum,
    float* __restrict__ possim, int* __restrict__ doneCount,
    float* __restrict__ out) {
  __shared__ float redBuf[4 * 16 * 68];   // 17408 B transpose-reduce buffer
  __shared__ float colAcc[TILE];
  __shared__ int lastFlag;

  const int t = blockIdx.x;
  int by = (int)((129.0f - sqrtf(129.0f * 129.0f - 8.0f * (float)t)) * 0.5f);
  if (by > NT - 1) by = NT - 1;
  if (by < 0) by = 0;
  while ((by + 1) * (129 - (by + 1)) / 2 <= t) ++by;
  while (by * (129 - by) / 2 > t) --by;
  const int bx = by + (t - by * (129 - by) / 2);
  const bool diagTile = (bx == by);

  const int rowBase = by * TILE;
  const int colBase = bx * TILE;

  const int tid   = threadIdx.x;
  const int lane  = tid & 63;
  const int wv    = tid >> 6;
  const int waveM = wv >> 1;
  const int waveN = wv & 1;
  const int quad  = lane >> 4;
  const int l15   = lane & 15;

  if (tid < TILE) colAcc[tid] = 0.0f;

  f32x4 acc[4][4] = {};

  // per-lane fragment base pointers (16B each; k advances via imm offset)
  const char* aP[4];
  const char* bP[4];
#pragma unroll
  for (int i = 0; i < 4; ++i) {
    const int ra = rowBase + waveM * 64 + i * 16 + l15;
    aP[i] = (const char*)(F + (size_t)ra * DIM) + quad * 16;
    const int rb = colBase + waveN * 64 + i * 16 + l15;
    bP[i] = (const char*)(F + (size_t)rb * DIM) + quad * 16;
  }

#pragma unroll
  for (int kc = 0; kc < 16; ++kc) {
    short8 a[4], b[4];
#pragma unroll
    for (int i = 0; i < 4; ++i) {
      a[i] = *(const short8*)(aP[i] + kc * 64);
      b[i] = *(const short8*)(bP[i] + kc * 64);
    }
#pragma unroll
    for (int mi = 0; mi < 4; ++mi)
#pragma unroll
      for (int ni = 0; ni < 4; ++ni)
        acc[mi][ni] =
            __builtin_amdgcn_mfma_f32_16x16x32_bf16(a[mi], b[ni], acc[mi][ni], 0, 0, 0);
  }

  __syncthreads();   // colAcc zero-init visible before epilogue atomics

  // --- epilogue ---
  f32x4 rsumv[4] = {};
  float colpart[4] = {0.0f, 0.0f, 0.0f, 0.0f};

  if (diagTile) {
#pragma unroll
    for (int mi = 0; mi < 4; ++mi)
#pragma unroll
      for (int ni = 0; ni < 4; ++ni)
#pragma unroll
        for (int r = 0; r < 4; ++r) {
          const int rl = waveM * 64 + mi * 16 + quad * 4 + r;
          const int cl = waveN * 64 + ni * 16 + l15;
          rsumv[mi][r] += (cl == rl) ? 0.0f : exp2f(acc[mi][ni][r]);
        }
  } else {
    const bool hasPos = (bx == by + 32);
#pragma unroll
    for (int mi = 0; mi < 4; ++mi)
#pragma unroll
      for (int ni = 0; ni < 4; ++ni)
#pragma unroll
        for (int r = 0; r < 4; ++r) {
          const float s = acc[mi][ni][r];
          const float e = exp2f(s);
          rsumv[mi][r] += e;
          colpart[ni] += e;
          if (hasPos) {
            const int rl = waveM * 64 + mi * 16 + quad * 4 + r;
            const int cl = waveN * 64 + ni * 16 + l15;
            if (cl == rl) {
              const int gi = rowBase + rl;
              possim[gi] = s;
              possim[gi + 4096] = s;
            }
          }
        }
  }

  // transpose-store row partials: [waveN][waveM][l15][mi*16+quad*4 .. +3]
  {
    float* wbase = redBuf + ((waveN * 2 + waveM) * 16 + l15) * 68 + quad * 4;
#pragma unroll
    for (int mi = 0; mi < 4; ++mi)
      *(f32x4*)(wbase + mi * 16) = rsumv[mi];
  }

  if (!diagTile) {
#pragma unroll
    for (int ni = 0; ni < 4; ++ni) {
      float c = colpart[ni];
      c += __shfl_xor(c, 16, 64);
      c += __shfl_xor(c, 32, 64);
      if (quad == 0) atomicAdd(&colAcc[waveN * 64 + ni * 16 + l15], c);
    }
  }
  __syncthreads();

  // 256 threads: each sums one (row, waveN-half) = 16 strided floats
  {
    const int wn = tid >> 7, r = tid & 127;
    const int strip = r >> 6, rl = r & 63;
    const float* base = redBuf + ((wn * 2 + strip) * 16) * 68 + rl;
    float s = 0.0f;
#pragma unroll
    for (int j = 0; j < 16; ++j) s += base[j * 68];
    atomicAdd(&rowsum[rowBase + r], s);
  }
  if (tid < TILE && !diagTile)
    atomicAdd(&rowsum[colBase + tid], colAcc[tid]);

  // --- fused finalize: last block computes the loss ---
  __syncthreads();                 // this block's atomics issued
  if (tid == 0) {
    __threadfence();               // release our writes
    const int prev = atomicAdd(doneCount, 1);
    lastFlag = (prev == NPAIR - 1) ? 1 : 0;
  }
  __syncthreads();
  if (lastFlag) {
    __threadfence();               // acquire: see all blocks' writes
    volatile const float* rs = rowsum;
    volatile const float* ps = possim;
    float acc2 = 0.0f;
    for (int i = tid; i < BATCH; i += 256)
      acc2 += __logf(rs[i]) - ps[i] * LN2;
#pragma unroll
    for (int m = 32; m > 0; m >>= 1) acc2 += __shfl_xor(acc2, m, 64);
    if (lane == 0) redBuf[wv] = acc2;
    __syncthreads();
    if (tid == 0)
      out[0] = (redBuf[0] + redBuf[1] + redBuf[2] + redBuf[3]) *
               (1.0f / (float)BATCH);
  }
}

extern "C" void kernel_launch(void* const* d_in, const int* in_sizes, int n_in,
                              void* d_out, int out_size, void* d_ws, size_t ws_size,
                              hipStream_t stream) {
  const float* x = (const float*)d_in[0];
  float* out = (float*)d_out;

  __hip_bfloat16* Fb = (__hip_bfloat16*)d_ws;
  float* rowsum = (float*)((char*)d_ws + (size_t)BATCH * DIM * sizeof(__hip_bfloat16));
  float* possim = rowsum + BATCH;
  int* doneCount = (int*)(possim + BATCH);

  normalize_bf16<<<BATCH / 4, 256, 0, stream>>>(x, Fb, rowsum, doneCount);
  sim_lse_kernel<<<NPAIR, 256, 0, stream>>>(Fb, rowsum, possim, doneCount, out);
}

// Round 7
// 182.173 us; speedup vs baseline: 1.3319x; 1.3319x over previous
//
#include <hip/hip_runtime.h>
#include <hip/hip_bf16.h>
#include <stdint.h>

#define BATCH 8192
#define DIM   512
#define TILE  128
#define NT    (BATCH / TILE)          // 64 tiles per dim
#define NPAIR (NT * (NT + 1) / 2)     // 2080 upper-triangle tile pairs

// Fb = F_norm * sqrt(log2(e)/T) so acc = Fb·Fbᵀ is already log2-domain logits.
#define FEAT_SCALE 4.5398164f         // sqrt(1.4426950409/0.07)
#define LN2        0.69314718055994531f

typedef __attribute__((ext_vector_type(8))) short short8;
typedef __attribute__((ext_vector_type(4))) float f32x4;

// ---------------------------------------------------------------------------
// Packed fragment layout: group g = row>>4 (16 rows, 16 KB each).
// Element offset (bf16) of chunk (kc, quad, l15):  g*8192 + kc*512 + quad*128
// + l15*8, holding F_norm[g*16+l15][kc*32 + quad*8 .. +8] — exactly the
// 16x16x32 MFMA A/B operand fragment. A wave's fragment load (fixed g, kc)
// has lane offset (quad*16+l15)*16B -> ONE coalesced 1 KB global_load_dwordx4
// (round 6's fatal 1KB-stride divergence eliminated at the layout level).
// ---------------------------------------------------------------------------

// Kernel 1: row-normalize fp32 -> bf16 * FEAT_SCALE, written in packed
// fragment order. One wave per row; lane owns k = 8*lane .. 8*lane+8.
__global__ __launch_bounds__(256) void normalize_pack(
    const float* __restrict__ x, __hip_bfloat16* __restrict__ o,
    float* __restrict__ rowsum, int* __restrict__ doneCount) {
  const int wv = threadIdx.x >> 6, lane = threadIdx.x & 63;
  const int row = blockIdx.x * 4 + wv;
  if (lane == 0) rowsum[row] = 0.0f;
  if (blockIdx.x == 0 && threadIdx.x == 0) *doneCount = 0;
  const float4* xr = (const float4*)(x + (size_t)row * DIM);
  const float4 v0 = xr[2 * lane];
  const float4 v1 = xr[2 * lane + 1];
  float ss = v0.x * v0.x + v0.y * v0.y + v0.z * v0.z + v0.w * v0.w +
             v1.x * v1.x + v1.y * v1.y + v1.z * v1.z + v1.w * v1.w;
#pragma unroll
  for (int m = 32; m > 0; m >>= 1) ss += __shfl_xor(ss, m, 64);
  const float inv = FEAT_SCALE / fmaxf(sqrtf(ss), 1e-12f);
  short8 p;
  p[0] = (short)__bfloat16_as_ushort(__float2bfloat16(v0.x * inv));
  p[1] = (short)__bfloat16_as_ushort(__float2bfloat16(v0.y * inv));
  p[2] = (short)__bfloat16_as_ushort(__float2bfloat16(v0.z * inv));
  p[3] = (short)__bfloat16_as_ushort(__float2bfloat16(v0.w * inv));
  p[4] = (short)__bfloat16_as_ushort(__float2bfloat16(v1.x * inv));
  p[5] = (short)__bfloat16_as_ushort(__float2bfloat16(v1.y * inv));
  p[6] = (short)__bfloat16_as_ushort(__float2bfloat16(v1.z * inv));
  p[7] = (short)__bfloat16_as_ushort(__float2bfloat16(v1.w * inv));
  const int g = row >> 4, lr = row & 15;
  const int kc = lane >> 2, quad = lane & 3;   // lane owns chunk (kc, quad)
  *(short8*)(o + (size_t)g * 8192 + kc * 512 + quad * 128 + lr * 8) = p;
}

// ---------------------------------------------------------------------------
// Kernel 2: barrier-free K-loop, fragments loaded coalesced from packed F.
// No LDS / no __syncthreads until the epilogue -> loads pipeline across the
// whole K-loop under compiler vmcnt scheduling. 2x intra-block redundancy
// (A per waveN, B per waveM), all L2/L3-resident traffic.
// Epilogue: exp2 (log2-domain acc) -> LDS transpose reduce -> one global
// atomic per row-half; col sums (symmetry credit) via butterfly.
// Finalize fused: last block (device-scope done counter) computes the loss.
// ---------------------------------------------------------------------------
__global__ __launch_bounds__(256, 3) void sim_lse_kernel(
    const __hip_bfloat16* __restrict__ F, float* __restrict__ rowsum,
    float* __restrict__ possim, int* __restrict__ doneCount,
    float* __restrict__ out) {
  __shared__ float redBuf[4 * 16 * 68];   // 17408 B transpose-reduce buffer
  __shared__ float colAcc[TILE];
  __shared__ int lastFlag;

  const int t = blockIdx.x;
  int by = (int)((129.0f - sqrtf(129.0f * 129.0f - 8.0f * (float)t)) * 0.5f);
  if (by > NT - 1) by = NT - 1;
  if (by < 0) by = 0;
  while ((by + 1) * (129 - (by + 1)) / 2 <= t) ++by;
  while (by * (129 - by) / 2 > t) --by;
  const int bx = by + (t - by * (129 - by) / 2);
  const bool diagTile = (bx == by);

  const int rowBase = by * TILE;
  const int colBase = bx * TILE;

  const int tid   = threadIdx.x;
  const int lane  = tid & 63;
  const int wv    = tid >> 6;
  const int waveM = wv >> 1;
  const int waveN = wv & 1;
  const int quad  = lane >> 4;
  const int l15   = lane & 15;

  if (tid < TILE) colAcc[tid] = 0.0f;

  f32x4 acc[4][4] = {};

  // fragment base pointers: group = (tileBase>>4) + wave*4 + i, lane offset
  // (quad*16+l15)*16B  -> coalesced 1 KB per fragment load
  const char* aP[4];
  const char* bP[4];
#pragma unroll
  for (int i = 0; i < 4; ++i) {
    const int ga = (rowBase >> 4) + waveM * 4 + i;
    aP[i] = (const char*)(F + (size_t)ga * 8192) + (quad * 16 + l15) * 16;
    const int gb = (colBase >> 4) + waveN * 4 + i;
    bP[i] = (const char*)(F + (size_t)gb * 8192) + (quad * 16 + l15) * 16;
  }

#pragma unroll
  for (int kc = 0; kc < 16; ++kc) {
    short8 a[4], b[4];
#pragma unroll
    for (int i = 0; i < 4; ++i) {
      a[i] = *(const short8*)(aP[i] + kc * 1024);
      b[i] = *(const short8*)(bP[i] + kc * 1024);
    }
#pragma unroll
    for (int mi = 0; mi < 4; ++mi)
#pragma unroll
      for (int ni = 0; ni < 4; ++ni)
        acc[mi][ni] =
            __builtin_amdgcn_mfma_f32_16x16x32_bf16(a[mi], b[ni], acc[mi][ni], 0, 0, 0);
  }

  __syncthreads();   // colAcc zero-init visible before epilogue atomics

  // --- epilogue ---
  f32x4 rsumv[4] = {};
  float colpart[4] = {0.0f, 0.0f, 0.0f, 0.0f};

  if (diagTile) {
#pragma unroll
    for (int mi = 0; mi < 4; ++mi)
#pragma unroll
      for (int ni = 0; ni < 4; ++ni)
#pragma unroll
        for (int r = 0; r < 4; ++r) {
          const int rl = waveM * 64 + mi * 16 + quad * 4 + r;
          const int cl = waveN * 64 + ni * 16 + l15;
          rsumv[mi][r] += (cl == rl) ? 0.0f : exp2f(acc[mi][ni][r]);
        }
  } else {
    const bool hasPos = (bx == by + 32);
#pragma unroll
    for (int mi = 0; mi < 4; ++mi)
#pragma unroll
      for (int ni = 0; ni < 4; ++ni)
#pragma unroll
        for (int r = 0; r < 4; ++r) {
          const float s = acc[mi][ni][r];
          const float e = exp2f(s);
          rsumv[mi][r] += e;
          colpart[ni] += e;
          if (hasPos) {
            const int rl = waveM * 64 + mi * 16 + quad * 4 + r;
            const int cl = waveN * 64 + ni * 16 + l15;
            if (cl == rl) {
              const int gi = rowBase + rl;
              possim[gi] = s;
              possim[gi + 4096] = s;
            }
          }
        }
  }

  // transpose-store row partials: [waveN][waveM][l15][mi*16+quad*4 .. +3]
  {
    float* wbase = redBuf + ((waveN * 2 + waveM) * 16 + l15) * 68 + quad * 4;
#pragma unroll
    for (int mi = 0; mi < 4; ++mi)
      *(f32x4*)(wbase + mi * 16) = rsumv[mi];
  }

  if (!diagTile) {
#pragma unroll
    for (int ni = 0; ni < 4; ++ni) {
      float c = colpart[ni];
      c += __shfl_xor(c, 16, 64);
      c += __shfl_xor(c, 32, 64);
      if (quad == 0) atomicAdd(&colAcc[waveN * 64 + ni * 16 + l15], c);
    }
  }
  __syncthreads();

  // 256 threads: each sums one (row, waveN-half) = 16 strided floats
  {
    const int wn = tid >> 7, r = tid & 127;
    const int strip = r >> 6, rl = r & 63;
    const float* base = redBuf + ((wn * 2 + strip) * 16) * 68 + rl;
    float s = 0.0f;
#pragma unroll
    for (int j = 0; j < 16; ++j) s += base[j * 68];
    atomicAdd(&rowsum[rowBase + r], s);
  }
  if (tid < TILE && !diagTile)
    atomicAdd(&rowsum[colBase + tid], colAcc[tid]);

  // --- fused finalize: last block computes the loss ---
  __syncthreads();                 // this block's atomics issued
  if (tid == 0) {
    __threadfence();               // release our writes
    const int prev = atomicAdd(doneCount, 1);
    lastFlag = (prev == NPAIR - 1) ? 1 : 0;
  }
  __syncthreads();
  if (lastFlag) {
    __threadfence();               // acquire: see all blocks' writes
    volatile const float* rs = rowsum;
    volatile const float* ps = possim;
    float acc2 = 0.0f;
    for (int i = tid; i < BATCH; i += 256)
      acc2 += __logf(rs[i]) - ps[i] * LN2;
#pragma unroll
    for (int m = 32; m > 0; m >>= 1) acc2 += __shfl_xor(acc2, m, 64);
    if (lane == 0) redBuf[wv] = acc2;
    __syncthreads();
    if (tid == 0)
      out[0] = (redBuf[0] + redBuf[1] + redBuf[2] + redBuf[3]) *
               (1.0f / (float)BATCH);
  }
}

extern "C" void kernel_launch(void* const* d_in, const int* in_sizes, int n_in,
                              void* d_out, int out_size, void* d_ws, size_t ws_size,
                              hipStream_t stream) {
  const float* x = (const float*)d_in[0];
  float* out = (float*)d_out;

  __hip_bfloat16* Fb = (__hip_bfloat16*)d_ws;   // packed fragment layout, 8 MB
  float* rowsum = (float*)((char*)d_ws + (size_t)BATCH * DIM * sizeof(__hip_bfloat16));
  float* possim = rowsum + BATCH;
  int* doneCount = (int*)(possim + BATCH);

  normalize_pack<<<BATCH / 4, 256, 0, stream>>>(x, Fb, rowsum, doneCount);
  sim_lse_kernel<<<NPAIR, 256, 0, stream>>>(Fb, rowsum, possim, doneCount, out);
}

// Round 8
// 143.166 us; speedup vs baseline: 1.6948x; 1.2725x over previous
//
#include <hip/hip_runtime.h>
#include <hip/hip_bf16.h>
#include <stdint.h>

#define BATCH 8192
#define DIM   512
#define TILE  128
#define BK    64                      // fp8 elements per K-slab
#define NITER (DIM / BK)              // 8
#define NT    (BATCH / TILE)          // 64 tiles per dim
#define NPAIR (NT * (NT + 1) / 2)     // 2080 upper-triangle tile pairs

// Fb = F_norm * sqrt(log2(e)/T) so acc = Fb·Fbᵀ is already log2-domain logits.
#define FEAT_SCALE 4.5398164f         // sqrt(1.4426950409/0.07)
#define LN2        0.69314718055994531f

typedef __attribute__((ext_vector_type(4))) float f32x4;
typedef __attribute__((ext_vector_type(2))) long long2_t;

__device__ __forceinline__ void gld_lds16(const void* g, void* l) {
  __builtin_amdgcn_global_load_lds(
      (__attribute__((address_space(1))) void*)(uintptr_t)g,
      (__attribute__((address_space(3))) void*)(uintptr_t)l,
      16, 0, 0);
}

// ---------------------------------------------------------------------------
// fp8 packed layout, 512 B per row. Row = 8 slabs of 64 B (BK=64). Within a
// slab, 16B slot q holds orig k in {q*8..q*8+8} ∪ {32+q*8..32+q*8+8} — the
// k-permutation that lets ONE ds_read_b128 feed TWO 16x16x32 MFMA k-steps
// (low 8B = step ks=0 window, high 8B = ks=32 window). Any consistent k
// permutation is legal for a dot product.
// ---------------------------------------------------------------------------

// Kernel 1: row-normalize fp32 -> fp8 e4m3 * FEAT_SCALE, permuted-packed.
// One wave per row; lane L owns the 8 orig-k values
//   k = (L>>3)*64 + (L&1)*32 + ((L>>1)&3)*8 .. +8
// and writes them as 8 B at byte offset L*8 (perfectly coalesced).
__global__ __launch_bounds__(256) void normalize_pack_fp8(
    const float* __restrict__ x, unsigned char* __restrict__ o,
    float* __restrict__ rowsum, int* __restrict__ doneCount) {
  const int wv = threadIdx.x >> 6, lane = threadIdx.x & 63;
  const int row = blockIdx.x * 4 + wv;
  if (lane == 0) rowsum[row] = 0.0f;
  if (blockIdx.x == 0 && threadIdx.x == 0) *doneCount = 0;
  const float4* xr = (const float4*)(x + (size_t)row * DIM);
  const int idx4 = (lane >> 3) * 16 + (lane & 1) * 8 + ((lane >> 1) & 3) * 2;
  const float4 v0 = xr[idx4];
  const float4 v1 = xr[idx4 + 1];
  float ss = v0.x * v0.x + v0.y * v0.y + v0.z * v0.z + v0.w * v0.w +
             v1.x * v1.x + v1.y * v1.y + v1.z * v1.z + v1.w * v1.w;
#pragma unroll
  for (int m = 32; m > 0; m >>= 1) ss += __shfl_xor(ss, m, 64);
  const float inv = FEAT_SCALE / fmaxf(sqrtf(ss), 1e-12f);
  int lo = __builtin_amdgcn_cvt_pk_fp8_f32(v0.x * inv, v0.y * inv, 0, 0);
  lo = __builtin_amdgcn_cvt_pk_fp8_f32(v0.z * inv, v0.w * inv, lo, 1);
  int hi = __builtin_amdgcn_cvt_pk_fp8_f32(v1.x * inv, v1.y * inv, 0, 0);
  hi = __builtin_amdgcn_cvt_pk_fp8_f32(v1.z * inv, v1.w * inv, hi, 1);
  int2 p; p.x = lo; p.y = hi;
  ((int2*)(o + (size_t)row * DIM))[lane] = p;
}

// ---------------------------------------------------------------------------
// Kernel 2: R4's proven 2-barrier K-loop structure, fp8 operands.
// Per iter: stage A slab (128x64B=8KB) + B slab via gld_lds16 (2+2 chunks
// per wave), barrier, 8 ds_read_b128 (each feeds 2 MFMA k-steps), 32 MFMAs,
// barrier. LDS bytes halved vs bf16 R4; same barrier count.
// 64B-row/4-slot XOR swizzle (slot ^ ((row>>1)&3)) — 0 conflicts measured R1.
// Epilogue: exp2 -> LDS transpose reduce -> 1 atomic/row-half; col sums via
// butterfly (symmetry credit). Finalize fused into the last block.
// ---------------------------------------------------------------------------
__global__ __launch_bounds__(256, 4) void sim_lse_kernel(
    const unsigned char* __restrict__ F, float* __restrict__ rowsum,
    float* __restrict__ possim, int* __restrict__ doneCount,
    float* __restrict__ out) {
  __shared__ char smem[16384];            // A [0,8K), B [8K,16K)
  __shared__ float redBuf[4 * 16 * 68];   // 17408 B transpose-reduce buffer
  __shared__ float colAcc[TILE];
  __shared__ int lastFlag;

  const int t = blockIdx.x;
  int by = (int)((129.0f - sqrtf(129.0f * 129.0f - 8.0f * (float)t)) * 0.5f);
  if (by > NT - 1) by = NT - 1;
  if (by < 0) by = 0;
  while ((by + 1) * (129 - (by + 1)) / 2 <= t) ++by;
  while (by * (129 - by) / 2 > t) --by;
  const int bx = by + (t - by * (129 - by) / 2);
  const bool diagTile = (bx == by);

  const int rowBase = by * TILE;
  const int colBase = bx * TILE;

  const int tid   = threadIdx.x;
  const int lane  = tid & 63;
  const int wv    = tid >> 6;
  const int waveM = wv >> 1;
  const int waveN = wv & 1;
  const int quad  = lane >> 4;
  const int l15   = lane & 15;

  if (tid < TILE) colAcc[tid] = 0.0f;

  f32x4 acc[4][4] = {};

  // staging: slab = 8 chunks of 16 rows (1 KB each); wave wv stages chunks
  // {2wv, 2wv+1} of A and of B. Source slot pre-permuted for the LDS swizzle.
  const int sb  = lane & 3;               // 16B slot within 64B slab-row
  const int r16 = lane >> 2;              // row within 16-row chunk
  const unsigned char* gA[2];
  const unsigned char* gB[2];
  char* ldsA[2];
  char* ldsB[2];
#pragma unroll
  for (int c = 0; c < 2; ++c) {
    const int sRow = wv * 32 + c * 16 + r16;
    const int g = sb ^ ((sRow >> 1) & 3);
    gA[c] = F + (size_t)(rowBase + sRow) * DIM + g * 16;
    gB[c] = F + (size_t)(colBase + sRow) * DIM + g * 16;
    ldsA[c] = smem + (wv * 2 + c) * 1024;
    ldsB[c] = smem + 8192 + (wv * 2 + c) * 1024;
  }

  // fragment LDS offsets (one b128 per fragment-pair, feeds 2 k-steps)
  int aOff[4], bOff[4];
#pragma unroll
  for (int i = 0; i < 4; ++i) {
    const int Ra = waveM * 64 + i * 16 + l15;
    aOff[i] = Ra * 64 + (quad ^ ((Ra >> 1) & 3)) * 16;
    const int Rb = waveN * 64 + i * 16 + l15;
    bOff[i] = 8192 + Rb * 64 + (quad ^ ((Rb >> 1) & 3)) * 16;
  }

  for (int kc = 0; kc < NITER; ++kc) {
    const int kb = kc * 64;               // byte offset of slab in row
#pragma unroll
    for (int c = 0; c < 2; ++c) {
      gld_lds16(gA[c] + kb, ldsA[c]);
      gld_lds16(gB[c] + kb, ldsB[c]);
    }
    __syncthreads();

    long2_t a[4], b[4];
#pragma unroll
    for (int i = 0; i < 4; ++i) {
      a[i] = *(const long2_t*)(smem + aOff[i]);
      b[i] = *(const long2_t*)(smem + bOff[i]);
    }
#pragma unroll
    for (int mi = 0; mi < 4; ++mi)
#pragma unroll
      for (int ni = 0; ni < 4; ++ni) {
        acc[mi][ni] = __builtin_amdgcn_mfma_f32_16x16x32_fp8_fp8(
            a[mi].x, b[ni].x, acc[mi][ni], 0, 0, 0);
        acc[mi][ni] = __builtin_amdgcn_mfma_f32_16x16x32_fp8_fp8(
            a[mi].y, b[ni].y, acc[mi][ni], 0, 0, 0);
      }
    __syncthreads();
  }

  // --- epilogue ---
  f32x4 rsumv[4] = {};
  float colpart[4] = {0.0f, 0.0f, 0.0f, 0.0f};

  if (diagTile) {
#pragma unroll
    for (int mi = 0; mi < 4; ++mi)
#pragma unroll
      for (int ni = 0; ni < 4; ++ni)
#pragma unroll
        for (int r = 0; r < 4; ++r) {
          const int rl = waveM * 64 + mi * 16 + quad * 4 + r;
          const int cl = waveN * 64 + ni * 16 + l15;
          rsumv[mi][r] += (cl == rl) ? 0.0f : exp2f(acc[mi][ni][r]);
        }
  } else {
    const bool hasPos = (bx == by + 32);
#pragma unroll
    for (int mi = 0; mi < 4; ++mi)
#pragma unroll
      for (int ni = 0; ni < 4; ++ni)
#pragma unroll
        for (int r = 0; r < 4; ++r) {
          const float s = acc[mi][ni][r];
          const float e = exp2f(s);
          rsumv[mi][r] += e;
          colpart[ni] += e;
          if (hasPos) {
            const int rl = waveM * 64 + mi * 16 + quad * 4 + r;
            const int cl = waveN * 64 + ni * 16 + l15;
            if (cl == rl) {
              const int gi = rowBase + rl;
              possim[gi] = s;
              possim[gi + 4096] = s;
            }
          }
        }
  }

  // transpose-store row partials: [waveN][waveM][l15][mi*16+quad*4 .. +3]
  {
    float* wbase = redBuf + ((waveN * 2 + waveM) * 16 + l15) * 68 + quad * 4;
#pragma unroll
    for (int mi = 0; mi < 4; ++mi)
      *(f32x4*)(wbase + mi * 16) = rsumv[mi];
  }

  if (!diagTile) {
#pragma unroll
    for (int ni = 0; ni < 4; ++ni) {
      float c = colpart[ni];
      c += __shfl_xor(c, 16, 64);
      c += __shfl_xor(c, 32, 64);
      if (quad == 0) atomicAdd(&colAcc[waveN * 64 + ni * 16 + l15], c);
    }
  }
  __syncthreads();

  // 256 threads: each sums one (row, waveN-half) = 16 strided floats
  {
    const int wn = tid >> 7, r = tid & 127;
    const int strip = r >> 6, rl = r & 63;
    const float* base = redBuf + ((wn * 2 + strip) * 16) * 68 + rl;
    float s = 0.0f;
#pragma unroll
    for (int j = 0; j < 16; ++j) s += base[j * 68];
    atomicAdd(&rowsum[rowBase + r], s);
  }
  if (tid < TILE && !diagTile)
    atomicAdd(&rowsum[colBase + tid], colAcc[tid]);

  // --- fused finalize: last block computes the loss ---
  __syncthreads();
  if (tid == 0) {
    __threadfence();
    const int prev = atomicAdd(doneCount, 1);
    lastFlag = (prev == NPAIR - 1) ? 1 : 0;
  }
  __syncthreads();
  if (lastFlag) {
    __threadfence();
    volatile const float* rs = rowsum;
    volatile const float* ps = possim;
    float acc2 = 0.0f;
    for (int i = tid; i < BATCH; i += 256)
      acc2 += __logf(rs[i]) - ps[i] * LN2;
#pragma unroll
    for (int m = 32; m > 0; m >>= 1) acc2 += __shfl_xor(acc2, m, 64);
    if (lane == 0) redBuf[wv] = acc2;
    __syncthreads();
    if (tid == 0)
      out[0] = (redBuf[0] + redBuf[1] + redBuf[2] + redBuf[3]) *
               (1.0f / (float)BATCH);
  }
}

extern "C" void kernel_launch(void* const* d_in, const int* in_sizes, int n_in,
                              void* d_out, int out_size, void* d_ws, size_t ws_size,
                              hipStream_t stream) {
  const float* x = (const float*)d_in[0];
  float* out = (float*)d_out;

  unsigned char* Fb = (unsigned char*)d_ws;   // fp8 packed, 4 MB
  float* rowsum = (float*)((char*)d_ws + (size_t)BATCH * DIM);
  float* possim = rowsum + BATCH;
  int* doneCount = (int*)(possim + BATCH);

  normalize_pack_fp8<<<BATCH / 4, 256, 0, stream>>>(x, Fb, rowsum, doneCount);
  sim_lse_kernel<<<NPAIR, 256, 0, stream>>>(Fb, rowsum, possim, doneCount, out);
}